// Round 5
// baseline (562.509 us; speedup 1.0000x reference)
//
#include <hip/hip_runtime.h>

// OmniShift collapsed to one effective 5x5 depthwise conv per channel.
// x: (8, 192, 256, 256) fp32. Memory-bound: 805 MB min -> ~128us @6.3TB/s.
//
// R5: rolling-window software pipeline (T14 async-STAGE split).
//  - One block per plane (1536 blocks). 36-row rolling LDS buffer, 16 phases
//    of 16 output rows. Per phase: issue next-tile global loads -> regs,
//    compute current tile from LDS, vmcnt(0), ds_write, stores, lgkmcnt(0)
//    + raw s_barrier (no vmcnt drain at barrier -> stores don't stall it).
//  - Zero halo overfetch (plane read exactly once): FETCH 453->403 MB.
//  - R4's measured 13.2us/CU-round ~= serialized mem(11.2)+compute(2.7);
//    this overlaps them within a block.

typedef float f32x4 __attribute__((ext_vector_type(4)));

constexpr int Bn = 8, Cn = 192, Hn = 256, Wn = 256;
constexpr int PH      = 16;          // output rows per phase
constexpr int NPH     = Hn / PH;     // 16 phases
constexpr int SLOTS   = 36;          // rolling LDS rows (20 window + 16 staging)
constexpr int LSTRIDE = 260;         // 2 + 256 + 2 (left pad 2 -> aligned reads)

__global__ __launch_bounds__(256, 4)
void omnishift_kernel(const float* __restrict__ x,
                      const float* __restrict__ w1,
                      const float* __restrict__ w3,
                      const float* __restrict__ w5,
                      const float* __restrict__ alpha,
                      float* __restrict__ out)
{
    __shared__ float lds[SLOTS * LSTRIDE];   // 37440 B -> 4 blocks/CU

    const int tid   = threadIdx.x;
    const int plane = blockIdx.x;            // b*C + c
    const int c     = plane % Cn;

    // ---- effective 5x5 weights (block-uniform -> scalar loads/SGPRs) ----
    const float a0 = alpha[0], a1 = alpha[1], a2 = alpha[2], a3 = alpha[3];
    float wf[5][5];
#pragma unroll
    for (int i = 0; i < 5; ++i)
#pragma unroll
        for (int j = 0; j < 5; ++j) {
            float v = a3 * w5[(c * 5 + i) * 5 + j];
            if (i >= 1 && i <= 3 && j >= 1 && j <= 3)
                v += a2 * w3[(c * 3 + (i - 1)) * 3 + (j - 1)];
            if (i == 2 && j == 2)
                v += a1 * w1[c] + a0;
            wf[i][j] = v;
        }

    const float* xp = x   + (size_t)plane * (Hn * Wn);
    float*       op = out + (size_t)plane * (Hn * Wn);

    // ---- zero halo columns of ALL slots once (never overwritten) ----
    if (tid < SLOTS * 4) {
        const int r   = tid >> 2;
        const int q   = tid & 3;
        const int col = (q < 2) ? q : (256 + q);   // 0,1,258,259
        lds[r * LSTRIDE + col] = 0.f;
    }

    // ---- prologue: rows -2..17 -> slots 0..19 (slot(r) = r+2) ----
#pragma unroll
    for (int i = 0; i < 5; ++i) {
        const int fidx = tid + i * 256;      // 0..1279 = 20 rows * 64 float4
        const int row  = fidx >> 6;          // wave-uniform
        const int l    = fidx & 63;
        const int gr   = row - 2;
        float4 v = make_float4(0.f, 0.f, 0.f, 0.f);
        if (gr >= 0) v = *reinterpret_cast<const float4*>(xp + gr * Wn + 4 * l);
        float* dst = &lds[row * LSTRIDE + 2 + 4 * l];
        *reinterpret_cast<float2*>(dst)     = make_float2(v.x, v.y);
        *reinterpret_cast<float2*>(dst + 2) = make_float2(v.z, v.w);
    }
    __syncthreads();

    const int ct  = tid & 63;    // column group: cols 4ct..4ct+3
    const int rg  = tid >> 6;    // row group within phase: rows 4rg..4rg+3
    const int oc0 = 4 * ct;

    int sbase = 0;               // (16p) mod 36; cycle period 9

#pragma unroll 1
    for (int p = 0; p < NPH; ++p) {
        // -- 1) issue prefetch: input rows 16p+18 .. 16p+33 -> regs --
        float4 st[4];
        if (p < NPH - 1) {
#pragma unroll
            for (int i = 0; i < 4; ++i) {
                const int fidx = tid + i * 256;
                const int row  = fidx >> 6;          // wave-uniform
                const int l    = fidx & 63;
                const int gr   = PH * p + 18 + row;
                st[i] = make_float4(0.f, 0.f, 0.f, 0.f);
                if (gr < Hn)
                    st[i] = *reinterpret_cast<const float4*>(xp + gr * Wn + 4 * l);
            }
        }

        // -- 2) compute output rows 16p+4rg .. +3 (5x8 sliding window) --
        float win[5][8];
#pragma unroll
        for (int i = 0; i < 4; ++i) {
            int slot = sbase + 4 * rg + i; if (slot >= SLOTS) slot -= SLOTS;
            const float* src = &lds[slot * LSTRIDE + oc0];   // 16B aligned
#pragma unroll
            for (int j = 0; j < 8; ++j) win[i][j] = src[j];
        }

        f32x4 o[4];
#pragma unroll
        for (int k = 0; k < 4; ++k) {
            int slot = sbase + 4 * rg + 4 + k; if (slot >= SLOTS) slot -= SLOTS;
            const float* src = &lds[slot * LSTRIDE + oc0];
#pragma unroll
            for (int j = 0; j < 8; ++j) win[4][j] = src[j];

#pragma unroll
            for (int jj = 0; jj < 4; ++jj) {
                float acc = 0.f;
#pragma unroll
                for (int i = 0; i < 5; ++i)
#pragma unroll
                    for (int d = 0; d < 5; ++d)
                        acc += win[i][jj + d] * wf[i][d];
                o[k][jj] = acc;
            }
#pragma unroll
            for (int i = 0; i < 4; ++i)
#pragma unroll
                for (int j = 0; j < 8; ++j) win[i][j] = win[i + 1][j];
        }

        // -- 3) drain prefetch loads, write them to rolling slots --
        if (p < NPH - 1) {
            asm volatile("s_waitcnt vmcnt(0)" ::: "memory");
#pragma unroll
            for (int i = 0; i < 4; ++i) {
                const int fidx = tid + i * 256;
                const int row  = fidx >> 6;
                const int l    = fidx & 63;
                int slot = sbase + 20 + row; if (slot >= SLOTS) slot -= SLOTS;
                float* dst = &lds[slot * LSTRIDE + 2 + 4 * l];
                *reinterpret_cast<float2*>(dst)     = make_float2(st[i].x, st[i].y);
                *reinterpret_cast<float2*>(dst + 2) = make_float2(st[i].z, st[i].w);
            }
        }

        // -- 4) output stores (after the vmcnt asm -> not drained this phase) --
        float* outp = op + (size_t)(PH * p + 4 * rg) * Wn + oc0;
#pragma unroll
        for (int k = 0; k < 4; ++k)
            *reinterpret_cast<f32x4*>(outp + (size_t)k * Wn) = o[k];

        // -- 5) barrier: LDS drained, but do NOT drain global stores --
        if (p < NPH - 1) {
            asm volatile("s_waitcnt lgkmcnt(0)" ::: "memory");
            __builtin_amdgcn_s_barrier();
        }

        sbase += PH; if (sbase >= SLOTS) sbase -= SLOTS;
    }
}

extern "C" void kernel_launch(void* const* d_in, const int* in_sizes, int n_in,
                              void* d_out, int out_size, void* d_ws, size_t ws_size,
                              hipStream_t stream)
{
    const float* x     = (const float*)d_in[0];
    const float* w1    = (const float*)d_in[1];
    const float* w3    = (const float*)d_in[2];
    const float* w5    = (const float*)d_in[3];
    const float* alpha = (const float*)d_in[4];
    float* out = (float*)d_out;

    omnishift_kernel<<<Bn * Cn, 256, 0, stream>>>(x, w1, w3, w5, alpha, out);
}

// Round 6
// 156.569 us; speedup vs baseline: 3.5927x; 3.5927x over previous
//
#include <hip/hip_runtime.h>

// OmniShift collapsed to one effective 5x5 depthwise conv per channel.
// x: (8, 192, 256, 256) fp32. Memory-bound: 805 MB min -> ~128us @6.3TB/s.
//
// R6: T14 rolling pipeline, spill-proofed.
//  R5 failed on register spills (VGPR_Count=64 vs ~112 live; FETCH/WRITE 2.5x
//  from scratch traffic) caused by the __launch_bounds__ min-occupancy hint.
//  - __launch_bounds__(256) only: allocator free (~115-130 VGPR); LDS 33.3KB
//    still gives 4 blocks/CU.
//  - One block per HALF-plane (3072 blocks = 12/CU, 3 clean rounds).
//  - Ring of 32 rows (AND-mask slots, sbase constant-folded per phase).
//  - Per phase: issue next-16-rows loads -> regs, compute 16 rows from LDS,
//    [lgkmcnt(0); s_barrier], ds_write staged regs, output stores,
//    [lgkmcnt(0); s_barrier]. vmcnt never drained at barriers.

typedef float f32x4 __attribute__((ext_vector_type(4)));

constexpr int Bn = 8, Cn = 192, Hn = 256, Wn = 256;
constexpr int HALF    = 128;         // output rows per block
constexpr int PH      = 16;          // output rows per phase
constexpr int NPH     = HALF / PH;   // 8 phases
constexpr int SLOTS   = 32;          // ring rows (20 window + 16 staged, wraps)
constexpr int LSTRIDE = 260;         // 2 + 256 + 2 (left pad 2 -> aligned reads)

__global__ __launch_bounds__(256)
void omnishift_kernel(const float* __restrict__ x,
                      const float* __restrict__ w1,
                      const float* __restrict__ w3,
                      const float* __restrict__ w5,
                      const float* __restrict__ alpha,
                      float* __restrict__ out)
{
    __shared__ float lds[SLOTS * LSTRIDE];   // 33280 B -> 4 blocks/CU

    const int tid   = threadIdx.x;
    const int wg    = blockIdx.x;
    const int plane = wg >> 1;               // b*C + c
    const int half  = wg & 1;
    const int r0    = half * HALF;
    const int c     = plane % Cn;

    // ---- effective 5x5 weights (block-uniform) ----
    const float a0 = alpha[0], a1 = alpha[1], a2 = alpha[2], a3 = alpha[3];
    float wf[5][5];
#pragma unroll
    for (int i = 0; i < 5; ++i)
#pragma unroll
        for (int j = 0; j < 5; ++j) {
            float v = a3 * w5[(c * 5 + i) * 5 + j];
            if (i >= 1 && i <= 3 && j >= 1 && j <= 3)
                v += a2 * w3[(c * 3 + (i - 1)) * 3 + (j - 1)];
            if (i == 2 && j == 2)
                v += a1 * w1[c] + a0;
            wf[i][j] = v;
        }

    const float* xp = x   + (size_t)plane * (Hn * Wn);
    float*       op = out + (size_t)plane * (Hn * Wn);

    // ---- zero halo columns of all 32 ring slots once ----
    if (tid < SLOTS * 4) {
        const int r   = tid >> 2;
        const int q   = tid & 3;
        const int col = (q < 2) ? q : (256 + q);   // 0,1,258,259
        lds[r * LSTRIDE + col] = 0.f;
    }

    // ---- prologue: rows rr=-2..17 -> slots 0..19 (slot(rr) = (rr+2)&31) ----
#pragma unroll
    for (int i = 0; i < 5; ++i) {
        const int fidx = tid + i * 256;      // 20 rows * 64 float4
        const int row  = fidx >> 6;          // wave-uniform
        const int l    = fidx & 63;
        const int gr   = r0 + row - 2;
        float4 v = make_float4(0.f, 0.f, 0.f, 0.f);
        if ((unsigned)gr < (unsigned)Hn)
            v = *reinterpret_cast<const float4*>(xp + gr * Wn + 4 * l);
        float* dst = &lds[row * LSTRIDE + 2 + 4 * l];
        *reinterpret_cast<float2*>(dst)     = make_float2(v.x, v.y);
        *reinterpret_cast<float2*>(dst + 2) = make_float2(v.z, v.w);
    }
    __syncthreads();

    const int ct  = tid & 63;    // column group: cols 4ct..4ct+3
    const int rg  = tid >> 6;    // row group: phase rows 4rg..4rg+3
    const int oc0 = 4 * ct;

    auto phase = [&](const int p, const int sbase) {   // sbase = (16p)&31, literal
        // -- 1) issue prefetch: input rows rr = 16p+18 .. 16p+33 -> regs --
        float4 st[4];
        if (p < NPH - 1) {
#pragma unroll
            for (int i = 0; i < 4; ++i) {
                const int fidx = tid + i * 256;
                const int row  = fidx >> 6;          // wave-uniform
                const int l    = fidx & 63;
                const int gr   = r0 + PH * p + 18 + row;
                st[i] = make_float4(0.f, 0.f, 0.f, 0.f);
                if (gr < Hn)
                    st[i] = *reinterpret_cast<const float4*>(xp + gr * Wn + 4 * l);
            }
        }

        // -- 2) compute output rows rr = 16p+4rg .. +3 (5x8 sliding window) --
        float win[5][8];
#pragma unroll
        for (int i = 0; i < 4; ++i) {
            const int slot = (sbase + 4 * rg + i) & (SLOTS - 1);
            const float* src = &lds[slot * LSTRIDE + oc0];   // 16B aligned
#pragma unroll
            for (int j = 0; j < 8; ++j) win[i][j] = src[j];
        }

        f32x4 o[4];
#pragma unroll
        for (int k = 0; k < 4; ++k) {
            const int slot = (sbase + 4 * rg + 4 + k) & (SLOTS - 1);
            const float* src = &lds[slot * LSTRIDE + oc0];
#pragma unroll
            for (int j = 0; j < 8; ++j) win[4][j] = src[j];

#pragma unroll
            for (int jj = 0; jj < 4; ++jj) {
                float acc = 0.f;
#pragma unroll
                for (int i = 0; i < 5; ++i)
#pragma unroll
                    for (int d = 0; d < 5; ++d)
                        acc += win[i][jj + d] * wf[i][d];
                o[k][jj] = acc;
            }
#pragma unroll
            for (int i = 0; i < 4; ++i)
#pragma unroll
                for (int j = 0; j < 8; ++j) win[i][j] = win[i + 1][j];
        }

        if (p < NPH - 1) {
            // reads done -> allow overwrite of oldest 16 slots
            asm volatile("s_waitcnt lgkmcnt(0)\n\ts_barrier" ::: "memory");
            // -- 3) drain prefetch (implicit vmcnt on st use), write ring --
#pragma unroll
            for (int i = 0; i < 4; ++i) {
                const int fidx = tid + i * 256;
                const int row  = fidx >> 6;
                const int l    = fidx & 63;
                const int slot = (sbase + 20 + row) & (SLOTS - 1);
                float* dst = &lds[slot * LSTRIDE + 2 + 4 * l];
                *reinterpret_cast<float2*>(dst)     = make_float2(st[i].x, st[i].y);
                *reinterpret_cast<float2*>(dst + 2) = make_float2(st[i].z, st[i].w);
            }
        }

        // -- 4) output stores (vmcnt never drained for these) --
        float* outp = op + (size_t)(r0 + PH * p + 4 * rg) * Wn + oc0;
#pragma unroll
        for (int k = 0; k < 4; ++k)
            *reinterpret_cast<f32x4*>(outp + (size_t)k * Wn) = o[k];

        if (p < NPH - 1) {
            // ring writes visible before next phase's reads
            asm volatile("s_waitcnt lgkmcnt(0)\n\ts_barrier" ::: "memory");
        }
    };

#pragma unroll 1
    for (int pp = 0; pp < NPH / 2; ++pp) {
        phase(2 * pp,     0);    // 16*(2pp)   mod 32 = 0
        phase(2 * pp + 1, 16);   // 16*(2pp+1) mod 32 = 16
    }
}

extern "C" void kernel_launch(void* const* d_in, const int* in_sizes, int n_in,
                              void* d_out, int out_size, void* d_ws, size_t ws_size,
                              hipStream_t stream)
{
    const float* x     = (const float*)d_in[0];
    const float* w1    = (const float*)d_in[1];
    const float* w3    = (const float*)d_in[2];
    const float* w5    = (const float*)d_in[3];
    const float* alpha = (const float*)d_in[4];
    float* out = (float*)d_out;

    omnishift_kernel<<<Bn * Cn * 2, 256, 0, stream>>>(x, w1, w3, w5, alpha, out);
}